// Round 2
// baseline (353.674 us; speedup 1.0000x reference)
//
#include <hip/hip_runtime.h>

// ---------------------------------------------------------------------------
// Model_39676907883593: out = dropout(softmax((x1 @ (m @ n^T)) / 64)) @ q
//   B=16, S=2048, D=64, DV=512.  Dropout = JAX threefry, key 42, p_keep=0.75.
// R5 = R4 resubmit (container infra failure, no kernel diagnostic):
//   - K tiles read directly from L2 (Khi/Klo are 512KB, L2-resident) instead
//     of LDS staging: removes 8-way-conflicted ds_writes (9.4M conflict cyc),
//     the staging phase, and one barrier per iteration.
//   - Ps double-buffered -> exactly 1 __syncthreads per K-iter (was 3).
//   - log2(e) folded into K at build time -> bare v_exp_f32 (exp2f) per score.
//   - bf16 P pack via v_cvt_pk_bf16_f32 (1 inst per pair, was ~11 VALU ops).
//   - s_setprio(1) around PV MFMA cluster (T5).
//   - prep merged into ONE kernel (build_k reads m via LDS chunk staging,
//     mT eliminated): 3 launches -> 2.
//   - R5 delta: EXP2F macro replaced with plain exp2f() (same v_exp_f32).
// ---------------------------------------------------------------------------

typedef short  s8v __attribute__((ext_vector_type(8)));
typedef float  f4v __attribute__((ext_vector_type(4)));

__device__ __forceinline__ unsigned short f2bf(float f) {
  unsigned int u = __float_as_uint(f);
  u += 0x7fffu + ((u >> 16) & 1u);           // RNE
  return (unsigned short)(u >> 16);
}
__device__ __forceinline__ float bf2f(unsigned short h) {
  return __uint_as_float(((unsigned int)h) << 16);
}

// rotl via v_alignbit: ({x,x} >> (32-r)) == rotl(x, r)
__device__ __forceinline__ unsigned int rotl(unsigned int x, unsigned int r) {
  return __builtin_amdgcn_alignbit(x, x, 32u - r);
}

// ---- threefry2x32, key = (0, 42); partitionable counter (0, idx) ----------
__device__ __forceinline__ unsigned int jax_bits(unsigned int idx) {
  const unsigned int K0 = 0u, K1 = 42u, K2 = 0x1BD11BDAu ^ K0 ^ K1;
  unsigned int x0 = 0u, x1 = idx;
  x0 += K0; x1 += K1;
#define TF_R(r) { x0 += x1; x1 = rotl(x1, r); x1 ^= x0; }
  TF_R(13) TF_R(15) TF_R(26) TF_R(6)
  x0 += K1; x1 += K2 + 1u;
  TF_R(17) TF_R(29) TF_R(16) TF_R(24)
  x0 += K2; x1 += K0 + 2u;
  TF_R(13) TF_R(15) TF_R(26) TF_R(6)
  x0 += K0; x1 += K1 + 3u;
  TF_R(17) TF_R(29) TF_R(16) TF_R(24)
  x0 += K1; x1 += K2 + 4u;
  TF_R(13) TF_R(15) TF_R(26) TF_R(6)
  x0 += K2; x1 += K0 + 5u;
#undef TF_R
  return x0 ^ x1;
}

__device__ __forceinline__ f4v mfma16(s8v a, s8v b, f4v c) {
  return __builtin_amdgcn_mfma_f32_16x16x32_bf16(a, b, c, 0, 0, 0);
}

// ---------------------------------------------------------------------------
// prep_all: blockIdx [0,512)     -> build K (4 s-rows/block; m staged in LDS)
//           [512,1536)           -> x1 cast to bf16 (8 elems/thread)
//           [1536,1792)          -> transpose_q (qT[dv][s] bf16)
// K[s][d] = (sum_dv m[d][dv]*n[s][dv]) * log2(e)/64, split to bf16 hi/lo
// (log2e folded here so attn_main uses bare v_exp_f32 = exp2).
// ---------------------------------------------------------------------------
__global__ void prep_all(const float* __restrict__ x1, const float* __restrict__ q,
                         const float* __restrict__ m, const float* __restrict__ nmat,
                         unsigned short* __restrict__ Xhi, unsigned short* __restrict__ qT,
                         unsigned short* __restrict__ Khi, unsigned short* __restrict__ Klo) {
  const int blk = blockIdx.x;
  const int t = threadIdx.x;
  if (blk < 512) {                           // ---- build K ----
    __shared__ float Lm[64][68];             // m chunk [d][j], row=272B (16B-aligned)
    const int s = blk * 4 + (t >> 6);        // s row (wave-uniform)
    const int d = t & 63;
    float a0 = 0.f, a1 = 0.f, a2 = 0.f, a3 = 0.f;
    for (int ch = 0; ch < 8; ++ch) {
      const int dv0 = ch * 64;
      __syncthreads();                       // prev chunk reads done
#pragma unroll
      for (int k = 0; k < 4; ++k) {          // stage m[0:64][dv0:dv0+64]
        const int fi = t + k * 256;          // float4 index 0..1023
        const int row = fi >> 4, c4 = fi & 15;
        *(float4*)&Lm[row][c4 * 4] =
            *(const float4*)&m[(size_t)row * 512 + dv0 + c4 * 4];
      }
      __syncthreads();
      const float4* nv = (const float4*)&nmat[(size_t)s * 512 + dv0];
#pragma unroll
      for (int j4 = 0; j4 < 16; ++j4) {
        const float4 nf = nv[j4];
        const float4 mf = *(const float4*)&Lm[d][j4 * 4];
        a0 = fmaf(mf.x, nf.x, a0); a1 = fmaf(mf.y, nf.y, a1);
        a2 = fmaf(mf.z, nf.z, a2); a3 = fmaf(mf.w, nf.w, a3);
      }
    }
    const float kv = ((a0 + a1) + (a2 + a3)) * (1.44269504088896340736f / 64.0f);
    const unsigned short h = f2bf(kv);
    Khi[s * 64 + d] = h;
    Klo[s * 64 + d] = f2bf(kv - bf2f(h));
  } else if (blk < 1536) {                   // ---- cast x1 -> bf16 ----
    const int i = ((blk - 512) * 256 + t) * 8;   // 2,097,152 elems total
    float4 a = *(const float4*)&x1[i];
    float4 b = *(const float4*)&x1[i + 4];
    ushort4 o0, o1;
    o0.x = f2bf(a.x); o0.y = f2bf(a.y); o0.z = f2bf(a.z); o0.w = f2bf(a.w);
    o1.x = f2bf(b.x); o1.y = f2bf(b.y); o1.z = f2bf(b.z); o1.w = f2bf(b.w);
    *(ushort4*)&Xhi[i] = o0;
    *(ushort4*)&Xhi[i + 4] = o1;
  } else {                                   // ---- transpose_q ----
    __shared__ unsigned short tile[64][65];
    const int bb = blk - 1536;               // 0..255
    const int s0 = (bb >> 3) * 64;
    const int d0 = (bb & 7) * 64;
#pragma unroll
    for (int k = 0; k < 16; ++k) {
      int lin = t + k * 256;
      int r = lin >> 6, c = lin & 63;
      tile[c][r] = f2bf(q[(size_t)(s0 + r) * 512 + d0 + c]);
    }
    __syncthreads();
#pragma unroll
    for (int k = 0; k < 16; ++k) {
      int lin = t + k * 256;
      int rr = lin >> 6, cc = lin & 63;
      qT[(size_t)(d0 + rr) * 2048 + s0 + cc] = tile[rr][cc];
    }
  }
}

// ---------------------------------------------------------------------------
// main fused kernel: 512 blocks (b, rowTile64) x 512 threads (8 waves)
//   QK^T computes S^T (A = K keys from GLOBAL/L2, B = X rows).
//   wave w: QK rows (w&3)*16..+16, keys (w>>2)*64..+64 of the 128-key iter.
//   PV: wave w owns dv slice [w*64, w*64+64), O^T = V^T * P^T.
//   Ps double-buffered -> exactly one barrier per iteration.
// ---------------------------------------------------------------------------
__global__ __launch_bounds__(512, 4) void attn_main(
    const unsigned short* __restrict__ Xhi,
    const unsigned short* __restrict__ Khi, const unsigned short* __restrict__ Klo,
    const unsigned short* __restrict__ qT, float* __restrict__ out) {
  __shared__ unsigned short Ps[2][64][136];  // probs bf16, dbuf   34,816 B
  __shared__ float rsum[2][64];              //                       512 B

  const int tid  = threadIdx.x;
  const int wave = tid >> 6;
  const int lane = tid & 63;
  const int l15  = lane & 15;
  const int quad = lane >> 4;

  const int b    = blockIdx.x >> 5;          // 16 batches
  const int row0 = (blockIdx.x & 31) * 64;   // 32 row tiles

  const int qk_row = (wave & 3) * 16 + l15;  // row (local) this lane scores
  const int qk_kg  = (wave >> 2) * 64;       // key-group base within iter

  // ---- X B-frags (hi only), iter-invariant, in registers ----
  const size_t xg = ((size_t)(b * 2048 + row0 + qk_row)) * 64 + quad * 8;
  const s8v X0 = *(const s8v*)&Xhi[xg];
  const s8v X1 = *(const s8v*)&Xhi[xg + 32];

  f4v acc[4][4];                             // O^T: [mt(dv 16)][nt(row 16)]
#pragma unroll
  for (int mt = 0; mt < 4; ++mt)
#pragma unroll
    for (int nt = 0; nt < 4; ++nt) acc[mt][nt] = f4v{0.f, 0.f, 0.f, 0.f};
  float rs = 0.f;                            // rowsum partial for row qk_row

  const unsigned int idx_row =
      ((unsigned int)(b * 2048 + row0 + qk_row)) * 2048u;

  // per-lane bases (element units); K frag = keys qk_kg+nt*16+l15, d = quad*8
  const unsigned short* __restrict__ khp = Khi + ((qk_kg + l15) * 64 + quad * 8);
  const unsigned short* __restrict__ klp = Klo + ((qk_kg + l15) * 64 + quad * 8);
  const unsigned short* __restrict__ qvp = qT + ((wave * 64 + l15) * 2048 + quad * 8);

  for (int it = 0; it < 16; ++it) {
    const int kt = it * 128;
    unsigned short (*Pb)[136] = Ps[it & 1];

    // ---- QK^T -> S^T: 4 key-tiles of 16, K frags straight from L2 ----
#pragma unroll
    for (int nt = 0; nt < 4; ++nt) {
      const int ko = (kt + nt * 16) * 64;                // element offset
      s8v Kh0 = *(const s8v*)(khp + ko);
      s8v Kh1 = *(const s8v*)(khp + ko + 32);
      s8v Kl0 = *(const s8v*)(klp + ko);
      s8v Kl1 = *(const s8v*)(klp + ko + 32);
      f4v c = {0.f, 0.f, 0.f, 0.f};
      c = mfma16(Kh0, X0, c);  c = mfma16(Kh1, X1, c);   // Khi . x
      c = mfma16(Kl0, X0, c);  c = mfma16(Kl1, X1, c);   // Klo . x
      // C: m = key quad*4+r (consecutive keys), n = row l15
      const unsigned int idx0 = idx_row + (unsigned int)(kt + qk_kg + nt * 16 + quad * 4);
      float p[4];
#pragma unroll
      for (int r = 0; r < 4; ++r) {
        float e = exp2f(c[r]);                            // K carries log2e/64
        rs += e;                                          // denom: unmasked
        const unsigned int bits = jax_bits(idx0 + r);
        p[r] = (bits < 0xC0000000u) ? e : 0.0f;
      }
      unsigned int p01, p23;
      asm("v_cvt_pk_bf16_f32 %0, %1, %2" : "=v"(p01) : "v"(p[0]), "v"(p[1]));
      asm("v_cvt_pk_bf16_f32 %0, %1, %2" : "=v"(p23) : "v"(p[2]), "v"(p[3]));
      *(uint2*)&Pb[(wave & 3) * 16 + l15][qk_kg + nt * 16 + quad * 4] =
          make_uint2(p01, p23);
    }
    __syncthreads();                         // P[it&1] complete; the WAR on
                                             // re-use of this buffer at it+2
                                             // is covered by barrier it+1.

    // ---- PV: O^T = V^T * P^T, wave owns dv [wave*64, +64) ----
#pragma unroll
    for (int ks = 0; ks < 4; ++ks) {         // 32-key chunks
      s8v Va[4];
#pragma unroll
      for (int mt = 0; mt < 4; ++mt)
        Va[mt] = *(const s8v*)(qvp + mt * (16 * 2048) + kt + ks * 32);
      __builtin_amdgcn_s_setprio(1);
#pragma unroll
      for (int nt = 0; nt < 4; ++nt) {
        s8v Pf = *(const s8v*)&Pb[nt * 16 + l15][ks * 32 + quad * 8];
#pragma unroll
        for (int mt = 0; mt < 4; ++mt) acc[mt][nt] = mfma16(Va[mt], Pf, acc[mt][nt]);
      }
      __builtin_amdgcn_s_setprio(0);
    }
  }

  // ---- rowsum: sum across quads (lanes sharing l15), then across key-groups
  {
    float v = rs;
    v += __shfl_xor(v, 16);
    v += __shfl_xor(v, 32);
    if (quad == 0) rsum[wave >> 2][(wave & 3) * 16 + l15] = v;
  }
  __syncthreads();

  // ---- normalize + store: out[b][row][dv] = acc / (0.75 * rowsum) ----
#pragma unroll
  for (int nt = 0; nt < 4; ++nt) {
    const int rloc = nt * 16 + l15;
    const int row = row0 + rloc;
    const float inv = 1.0f / (0.75f * (rsum[0][rloc] + rsum[1][rloc]));
    const size_t base = ((size_t)(b * 2048 + row)) * 512 + wave * 64;
#pragma unroll
    for (int mt = 0; mt < 4; ++mt) {
      f4v v = acc[mt][nt];
      v[0] *= inv; v[1] *= inv; v[2] *= inv; v[3] *= inv;
      *(f4v*)&out[base + mt * 16 + quad * 4] = v;
    }
  }
}

// ---------------------------------------------------------------------------
extern "C" void kernel_launch(void* const* d_in, const int* in_sizes, int n_in,
                              void* d_out, int out_size, void* d_ws, size_t ws_size,
                              hipStream_t stream) {
  (void)in_sizes; (void)n_in; (void)out_size; (void)ws_size;
  const float* x1 = (const float*)d_in[0];   // [16][2048][64]
  const float* m  = (const float*)d_in[1];   // [64][512]
  const float* n  = (const float*)d_in[2];   // [2048][512]
  const float* q  = (const float*)d_in[3];   // [2048][512]
  float* out = (float*)d_out;                // [16][2048][512]

  char* ws = (char*)d_ws;
  unsigned short* Khi = (unsigned short*)(ws);             //   262,144
  unsigned short* Klo = (unsigned short*)(ws + 262144);    //   262,144
  unsigned short* Xhi = (unsigned short*)(ws + 524288);    // 4,194,304
  unsigned short* qT  = (unsigned short*)(ws + 4718592);   // 2,097,152

  prep_all<<<1792, 256, 0, stream>>>(x1, q, m, n, Xhi, qT, Khi, Klo);
  attn_main<<<512, 512, 0, stream>>>(Xhi, Khi, Klo, qT, out);
}

// Round 4
// 312.268 us; speedup vs baseline: 1.1326x; 1.1326x over previous
//
#include <hip/hip_runtime.h>

// ---------------------------------------------------------------------------
// Model_39676907883593: out = dropout(softmax((x1 @ (m @ n^T)) / 64)) @ q
//   B=16, S=2048, D=64, DV=512.  Dropout = JAX threefry, key 42, p_keep=0.75.
// R7: 8-way KEY split in QK; K fragments in REGISTERS (no LDS for K at all):
//   - wave w owns keys [w*16, w*16+16) of each 128-key iter -> K reads are 1x
//     per block (R5 had 4x redundancy), straight from L2 into regs.
//   - K(it+1) frags loaded right after QK(it)'s last use of the regs ->
//     in flight across barrier + PV (~600 cyc) -> latency hidden; compiler
//     inserts the vmcnt wait at next QK top (FIFO: K loads are oldest).
//   - X tile in LDS (9 KB, iter-invariant addrs); keeps VGPR+AGPR <= 128.
//   - Ps double-buffered -> exactly ONE __syncthreads per iteration.
//   - No global_load_lds / no addrspace casts / no inline vmcnt (de-risk
//     after two container failures on R6-style submissions).
//   - exp2f with log2e folded into K; cvt_pk bf16 pack; setprio around PV.
// ---------------------------------------------------------------------------

typedef short  s8v __attribute__((ext_vector_type(8)));
typedef float  f4v __attribute__((ext_vector_type(4)));

__device__ __forceinline__ unsigned short f2bf(float f) {
  unsigned int u = __float_as_uint(f);
  u += 0x7fffu + ((u >> 16) & 1u);           // RNE
  return (unsigned short)(u >> 16);
}
__device__ __forceinline__ float bf2f(unsigned short h) {
  return __uint_as_float(((unsigned int)h) << 16);
}

// rotl via v_alignbit: ({x,x} >> (32-r)) == rotl(x, r)
__device__ __forceinline__ unsigned int rotl(unsigned int x, unsigned int r) {
  return __builtin_amdgcn_alignbit(x, x, 32u - r);
}

// ---- threefry2x32, key = (0, 42); partitionable counter (0, idx) ----------
__device__ __forceinline__ unsigned int jax_bits(unsigned int idx) {
  const unsigned int K0 = 0u, K1 = 42u, K2 = 0x1BD11BDAu ^ K0 ^ K1;
  unsigned int x0 = 0u, x1 = idx;
  x0 += K0; x1 += K1;
#define TF_R(r) { x0 += x1; x1 = rotl(x1, r); x1 ^= x0; }
  TF_R(13) TF_R(15) TF_R(26) TF_R(6)
  x0 += K1; x1 += K2 + 1u;
  TF_R(17) TF_R(29) TF_R(16) TF_R(24)
  x0 += K2; x1 += K0 + 2u;
  TF_R(13) TF_R(15) TF_R(26) TF_R(6)
  x0 += K0; x1 += K1 + 3u;
  TF_R(17) TF_R(29) TF_R(16) TF_R(24)
  x0 += K1; x1 += K2 + 4u;
  TF_R(13) TF_R(15) TF_R(26) TF_R(6)
  x0 += K2; x1 += K0 + 5u;
#undef TF_R
  return x0 ^ x1;
}

__device__ __forceinline__ f4v mfma16(s8v a, s8v b, f4v c) {
  return __builtin_amdgcn_mfma_f32_16x16x32_bf16(a, b, c, 0, 0, 0);
}

// ---------------------------------------------------------------------------
// prep_all (unchanged, verified in R5 run): build K (log2e/64 folded, hi/lo),
// cast x1 -> bf16, transpose q.
// ---------------------------------------------------------------------------
__global__ void prep_all(const float* __restrict__ x1, const float* __restrict__ q,
                         const float* __restrict__ m, const float* __restrict__ nmat,
                         unsigned short* __restrict__ Xhi, unsigned short* __restrict__ qT,
                         unsigned short* __restrict__ Khi, unsigned short* __restrict__ Klo) {
  const int blk = blockIdx.x;
  const int t = threadIdx.x;
  if (blk < 512) {                           // ---- build K ----
    __shared__ float Lm[64][68];
    const int s = blk * 4 + (t >> 6);
    const int d = t & 63;
    float a0 = 0.f, a1 = 0.f, a2 = 0.f, a3 = 0.f;
    for (int ch = 0; ch < 8; ++ch) {
      const int dv0 = ch * 64;
      __syncthreads();
#pragma unroll
      for (int k = 0; k < 4; ++k) {
        const int fi = t + k * 256;
        const int row = fi >> 4, c4 = fi & 15;
        *(float4*)&Lm[row][c4 * 4] =
            *(const float4*)&m[(size_t)row * 512 + dv0 + c4 * 4];
      }
      __syncthreads();
      const float4* nv = (const float4*)&nmat[(size_t)s * 512 + dv0];
#pragma unroll
      for (int j4 = 0; j4 < 16; ++j4) {
        const float4 nf = nv[j4];
        const float4 mf = *(const float4*)&Lm[d][j4 * 4];
        a0 = fmaf(mf.x, nf.x, a0); a1 = fmaf(mf.y, nf.y, a1);
        a2 = fmaf(mf.z, nf.z, a2); a3 = fmaf(mf.w, nf.w, a3);
      }
    }
    const float kv = ((a0 + a1) + (a2 + a3)) * (1.44269504088896340736f / 64.0f);
    const unsigned short h = f2bf(kv);
    Khi[s * 64 + d] = h;
    Klo[s * 64 + d] = f2bf(kv - bf2f(h));
  } else if (blk < 1536) {                   // ---- cast x1 -> bf16 ----
    const int i = ((blk - 512) * 256 + t) * 8;
    float4 a = *(const float4*)&x1[i];
    float4 b = *(const float4*)&x1[i + 4];
    ushort4 o0, o1;
    o0.x = f2bf(a.x); o0.y = f2bf(a.y); o0.z = f2bf(a.z); o0.w = f2bf(a.w);
    o1.x = f2bf(b.x); o1.y = f2bf(b.y); o1.z = f2bf(b.z); o1.w = f2bf(b.w);
    *(ushort4*)&Xhi[i] = o0;
    *(ushort4*)&Xhi[i + 4] = o1;
  } else {                                   // ---- transpose_q ----
    __shared__ unsigned short tile[64][65];
    const int bb = blk - 1536;
    const int s0 = (bb >> 3) * 64;
    const int d0 = (bb & 7) * 64;
#pragma unroll
    for (int k = 0; k < 16; ++k) {
      int lin = t + k * 256;
      int r = lin >> 6, c = lin & 63;
      tile[c][r] = f2bf(q[(size_t)(s0 + r) * 512 + d0 + c]);
    }
    __syncthreads();
#pragma unroll
    for (int k = 0; k < 16; ++k) {
      int lin = t + k * 256;
      int rr = lin >> 6, cc = lin & 63;
      qT[(size_t)(d0 + rr) * 2048 + s0 + cc] = tile[rr][cc];
    }
  }
}

// ---------------------------------------------------------------------------
// main fused kernel: 512 blocks (b, rowTile64) x 512 threads (8 waves)
//   QK^T: wave w owns keys [w*16, w*16+16) of the 128-key iter; computes
//   S^T[16 keys][64 rows] (A = K frags in REGISTERS, B = X from LDS).
//   PV: wave w owns dv slice [w*64, +64), O^T = V^T * P^T.
// ---------------------------------------------------------------------------
__global__ __launch_bounds__(512, 4) void attn_main(
    const unsigned short* __restrict__ Xhi,
    const unsigned short* __restrict__ Khi, const unsigned short* __restrict__ Klo,
    const unsigned short* __restrict__ qT, float* __restrict__ out) {
  __shared__ unsigned short Xs[64][72];      // X tile                 9216 B
  __shared__ unsigned short Ps[2][64][136];  // probs bf16, dbuf      34816 B
  __shared__ float rsum[8][64];              //                        2048 B

  const int tid  = threadIdx.x;
  const int wave = tid >> 6;
  const int lane = tid & 63;
  const int l15  = lane & 15;
  const int quad = lane >> 4;

  const int b    = blockIdx.x >> 5;          // 16 batches
  const int row0 = (blockIdx.x & 31) * 64;   // 32 row tiles

  // ---- stage X tile (64 rows x 64 d) ----
  {
    const int r = tid >> 3, c8 = (tid & 7) * 8;
    *(uint4*)&Xs[r][c8] =
        *(const uint4*)&Xhi[((size_t)(b * 2048 + row0 + r)) * 64 + c8];
  }

  // per-lane K frag bases: key = wave*16 + l15, d = quad*8 (hi half d<32)
  const unsigned short* __restrict__ khp = Khi + ((wave * 16 + l15) * 64 + quad * 8);
  const unsigned short* __restrict__ klp = Klo + ((wave * 16 + l15) * 64 + quad * 8);
  const unsigned short* __restrict__ qvp = qT + ((wave * 64 + l15) * 2048 + quad * 8);

  // ---- K(0) frags into registers ----
  s8v Kh0 = *(const s8v*)(khp);
  s8v Kh1 = *(const s8v*)(khp + 32);
  s8v Kl0 = *(const s8v*)(klp);
  s8v Kl1 = *(const s8v*)(klp + 32);

  f4v acc[4][4];                             // O^T: [mt(dv 16)][nt(row 16)]
#pragma unroll
  for (int mt = 0; mt < 4; ++mt)
#pragma unroll
    for (int nt = 0; nt < 4; ++nt) acc[mt][nt] = f4v{0.f, 0.f, 0.f, 0.f};
  float rs[4] = {0.f, 0.f, 0.f, 0.f};        // rowsum partials per nt

  const unsigned int idxl =
      ((unsigned int)(b * 2048 + row0 + l15)) * 2048u +
      (unsigned int)(wave * 16 + quad * 4);

  __syncthreads();                           // Xs staged

  for (int it = 0; it < 16; ++it) {
    const int kt = it * 128;
    unsigned short (*Pb)[136] = Ps[it & 1];

    // ---- QK^T -> S^T: 16 keys x 64 rows, K frags in regs ----
#pragma unroll
    for (int nt = 0; nt < 4; ++nt) {
      const s8v Xb0 = *(const s8v*)&Xs[nt * 16 + l15][quad * 8];
      const s8v Xb1 = *(const s8v*)&Xs[nt * 16 + l15][quad * 8 + 32];
      f4v c = {0.f, 0.f, 0.f, 0.f};
      c = mfma16(Kh0, Xb0, c);  c = mfma16(Kh1, Xb1, c);
      c = mfma16(Kl0, Xb0, c);  c = mfma16(Kl1, Xb1, c);
      // C: m = key quad*4+r, n = row l15 (row tile nt)
      const unsigned int idx0 = idxl + (unsigned int)(nt * 32768 + kt);
      float p[4];
#pragma unroll
      for (int r = 0; r < 4; ++r) {
        float e = exp2f(c[r]);                 // K carries log2e/64
        rs[nt] += e;                           // denom: unmasked
        const unsigned int bits = jax_bits(idx0 + r);
        p[r] = (bits < 0xC0000000u) ? e : 0.0f;
      }
      unsigned int p01, p23;
      asm("v_cvt_pk_bf16_f32 %0, %1, %2" : "=v"(p01) : "v"(p[0]), "v"(p[1]));
      asm("v_cvt_pk_bf16_f32 %0, %1, %2" : "=v"(p23) : "v"(p[2]), "v"(p[3]));
      *(uint2*)&Pb[nt * 16 + l15][wave * 16 + quad * 4] = make_uint2(p01, p23);
    }

    // ---- prefetch K(it+1) frags (last use of K regs was above) ----
    if (it < 15) {
      const int ko = (it + 1) * 8192;          // 128 keys * 64 d elements
      Kh0 = *(const s8v*)(khp + ko);
      Kh1 = *(const s8v*)(khp + ko + 32);
      Kl0 = *(const s8v*)(klp + ko);
      Kl1 = *(const s8v*)(klp + ko + 32);
    }

    __syncthreads();                          // Ps[it&1] complete (only barrier)

    // ---- PV: O^T = V^T * P^T, wave owns dv [wave*64, +64) ----
#pragma unroll
    for (int ks = 0; ks < 4; ++ks) {          // 32-key chunks
      s8v Va[4];
#pragma unroll
      for (int mt = 0; mt < 4; ++mt)
        Va[mt] = *(const s8v*)(qvp + mt * (16 * 2048) + kt + ks * 32);
      __builtin_amdgcn_s_setprio(1);
#pragma unroll
      for (int nt = 0; nt < 4; ++nt) {
        const s8v Pf = *(const s8v*)&Pb[nt * 16 + l15][ks * 32 + quad * 8];
#pragma unroll
        for (int mt = 0; mt < 4; ++mt) acc[mt][nt] = mfma16(Va[mt], Pf, acc[mt][nt]);
      }
      __builtin_amdgcn_s_setprio(0);
    }
  }

  // ---- rowsum: sum across quads, publish per-wave partials ----
#pragma unroll
  for (int nt = 0; nt < 4; ++nt) {
    float v = rs[nt];
    v += __shfl_xor(v, 16);
    v += __shfl_xor(v, 32);
    if (quad == 0) rsum[wave][nt * 16 + l15] = v;
  }
  __syncthreads();

  // ---- normalize + store: out[b][row][dv] = acc / (0.75 * rowsum) ----
#pragma unroll
  for (int nt = 0; nt < 4; ++nt) {
    const int rloc = nt * 16 + l15;
    float tot = 0.f;
#pragma unroll
    for (int w2 = 0; w2 < 8; ++w2) tot += rsum[w2][rloc];
    const float inv = 1.0f / (0.75f * tot);
    const size_t base = ((size_t)(b * 2048 + row0 + rloc)) * 512 + wave * 64;
#pragma unroll
    for (int mt = 0; mt < 4; ++mt) {
      f4v v = acc[mt][nt];
      v[0] *= inv; v[1] *= inv; v[2] *= inv; v[3] *= inv;
      *(f4v*)&out[base + mt * 16 + quad * 4] = v;
    }
  }
}

// ---------------------------------------------------------------------------
extern "C" void kernel_launch(void* const* d_in, const int* in_sizes, int n_in,
                              void* d_out, int out_size, void* d_ws, size_t ws_size,
                              hipStream_t stream) {
  (void)in_sizes; (void)n_in; (void)out_size; (void)ws_size;
  const float* x1 = (const float*)d_in[0];   // [16][2048][64]
  const float* m  = (const float*)d_in[1];   // [64][512]
  const float* n  = (const float*)d_in[2];   // [2048][512]
  const float* q  = (const float*)d_in[3];   // [2048][512]
  float* out = (float*)d_out;                // [16][2048][512]

  char* ws = (char*)d_ws;
  unsigned short* Khi = (unsigned short*)(ws);             //   262,144
  unsigned short* Klo = (unsigned short*)(ws + 262144);    //   262,144
  unsigned short* Xhi = (unsigned short*)(ws + 524288);    // 4,194,304
  unsigned short* qT  = (unsigned short*)(ws + 4718592);   // 2,097,152

  prep_all<<<1792, 256, 0, stream>>>(x1, q, m, n, Xhi, qT, Khi, Klo);
  attn_main<<<512, 512, 0, stream>>>(Xhi, Khi, Klo, qT, out);
}